// Round 4
// baseline (674.424 us; speedup 1.0000x reference)
//
#include <hip/hip_runtime.h>
#include <stdint.h>

#define E_    8
#define D_    2048
#define I_    1408
#define TWOI_ 2816
#define N_    8192
#define BM    128
#define MAXTILES 72
#define MPAD  9216
#define NCT1  22

typedef __bf16 bf16x8 __attribute__((ext_vector_type(8)));
typedef float  floatx4 __attribute__((ext_vector_type(4)));

// ---- meta layout (int offsets into ws) ----
#define M_CNT   0    // [8]
#define M_CUR   8    // [8]
#define M_PB    16   // padbase[8]
#define M_NT    24   // ntiles (128-row tiles)
#define M_RTE   32   // rt_expert[72]
#define M_RTR   104  // rt_row0[72]
#define M_RTV   176  // rt_nvalid[72]

// ---- ws byte offsets ----
#define OFF_PERM  4096ULL
#define OFF_WPAD  40960ULL
#define OFF_APAD  81920ULL
#define OFF_HPAD  37830656ULL
#define WS_NEED   63782912ULL

__device__ inline void gload16(const void* g, void* lds) {
  __builtin_amdgcn_global_load_lds(
      (__attribute__((address_space(1))) void*)g,
      (__attribute__((address_space(3))) void*)lds, 16, 0, 0);
}

__device__ inline unsigned short f2bf(float f) {
  unsigned int u = __builtin_bit_cast(unsigned int, f);
  u += 0x7fffu + ((u >> 16) & 1u);   // RNE; inputs finite
  return (unsigned short)(u >> 16);
}

// ---------------- routing (ballot-based) ----------------
__global__ void k_hist(const int* __restrict__ ids, int* meta) {
  int i = blockIdx.x * 256 + threadIdx.x;
  int e = ids[i];
  int lane = threadIdx.x & 63;
  for (int ex = 0; ex < E_; ++ex) {
    unsigned long long m = __ballot(e == ex);
    if (lane == 0 && m) atomicAdd(&meta[M_CNT + ex], __popcll(m));
  }
}

__global__ void k_meta(int* meta) {
  if (threadIdx.x != 0) return;
  int padr = 0, tiles = 0;
  for (int e = 0; e < E_; ++e) {
    meta[M_PB + e] = padr;
    int c = meta[M_CNT + e];
    int nt = (c + BM - 1) / BM;
    for (int t = 0; t < nt; ++t) {
      meta[M_RTE + tiles] = e;
      meta[M_RTR + tiles] = padr + t * BM;
      int v = c - t * BM; if (v > BM) v = BM;
      meta[M_RTV + tiles] = v;
      tiles++;
    }
    padr += nt * BM;
  }
  meta[M_NT] = tiles;
}

__global__ void k_scatter(const int* __restrict__ ids, const float* __restrict__ w,
                          int* meta, int* perm, float* wpad) {
  int i = blockIdx.x * 256 + threadIdx.x;
  int e = ids[i];
  float wv = w[i];
  int lane = threadIdx.x & 63;
  for (int ex = 0; ex < E_; ++ex) {
    unsigned long long m = __ballot(e == ex);
    if (!m) continue;
    int base = 0;
    if (lane == 0) base = atomicAdd(&meta[M_CUR + ex], __popcll(m));
    base = __shfl(base, 0);
    if (e == ex) {
      int r = meta[M_PB + ex] + base + __popcll(m & ((1ULL << lane) - 1ULL));
      perm[r] = i;
      wpad[r] = wv;
    }
  }
}

// -------------- gather tokens -> bf16 (permuted, padded) --------------
__global__ void k_gather(const float* __restrict__ tokens, const int* __restrict__ perm,
                         unsigned short* __restrict__ apad) {
  int r = blockIdx.x;
  int t = perm[r];
  if (t < 0) return;
  const float4* src = (const float4*)(tokens + (size_t)t * D_);
  uint4* dst = (uint4*)(apad + (size_t)r * D_);
  int i = threadIdx.x;
  float4 a = src[i * 2], b = src[i * 2 + 1];
  union { unsigned short s[8]; uint4 v; } pk;
  pk.s[0] = f2bf(a.x); pk.s[1] = f2bf(a.y); pk.s[2] = f2bf(a.z); pk.s[3] = f2bf(a.w);
  pk.s[4] = f2bf(b.x); pk.s[5] = f2bf(b.y); pk.s[6] = f2bf(b.z); pk.s[7] = f2bf(b.w);
  dst[i] = pk.v;
}

// =====================================================================
// GEMM1: fc1 = A @ gate_up^T (gate_up read DIRECTLY as fp32; converted
// to bf16 in-register after ds_read). Eliminates k_cvt's 277 MB.
// Structure = round-3 fine-block pipeline: 2 waves, BM=128, BN=64g+64u,
// BK=32, counted vmcnt(12), chunk-XOR swizzles both-sides.
// LDS: A bf16 2x8KB + Bg f32 2x8KB + Bu f32 2x8KB = 48 KB.
// =====================================================================

#define SB0() __builtin_amdgcn_sched_barrier(0);

// stage one K-step: A bf16 (4 gloads), Bg/Bu fp32 (4+4 gloads)
#define STG(s_)                                                        \
  gload16(pa,            &Ab[s_][tid8]);                               \
  gload16(pa +  32 * D_, &Ab[s_][1024 + tid8]);                        \
  gload16(pa +  64 * D_, &Ab[s_][2048 + tid8]);                        \
  gload16(pa +  96 * D_, &Ab[s_][3072 + tid8]);                        \
  gload16(pg,            &Bgs[s_][tid4]);                              \
  gload16(pg +  16 * D_, &Bgs[s_][ 512 + tid4]);                       \
  gload16(pg +  32 * D_, &Bgs[s_][1024 + tid4]);                       \
  gload16(pg +  48 * D_, &Bgs[s_][1536 + tid4]);                       \
  gload16(pu,            &Bus[s_][tid4]);                              \
  gload16(pu +  16 * D_, &Bus[s_][ 512 + tid4]);                       \
  gload16(pu +  32 * D_, &Bus[s_][1024 + tid4]);                       \
  gload16(pu +  48 * D_, &Bus[s_][1536 + tid4]);                       \
  pa += 32; pg += 32; pu += 32;

#define CVT8(dst, lo, hi)                                              \
  dst[0] = (__bf16)lo.x; dst[1] = (__bf16)lo.y;                        \
  dst[2] = (__bf16)lo.z; dst[3] = (__bf16)lo.w;                        \
  dst[4] = (__bf16)hi.x; dst[5] = (__bf16)hi.y;                        \
  dst[6] = (__bf16)hi.z; dst[7] = (__bf16)hi.w;

// read B frags (fp32, swizzled) + convert; then A frags (bf16, swizzled)
#define RD3(s_)                                                        \
  {                                                                    \
    _Pragma("unroll") for (int nf = 0; nf < 2; ++nf) {                 \
      const float* rw = &Bgs[s_][(wn * 32 + nf * 16 + l16) * 32];      \
      float4 lo = *(const float4*)(rw + loq);                          \
      float4 hi = *(const float4*)(rw + (loq ^ 4));                    \
      CVT8(bgf[nf], lo, hi)                                            \
    }                                                                  \
    _Pragma("unroll") for (int nf = 0; nf < 2; ++nf) {                 \
      const float* rw = &Bus[s_][(wn * 32 + nf * 16 + l16) * 32];      \
      float4 lo = *(const float4*)(rw + loq);                          \
      float4 hi = *(const float4*)(rw + (loq ^ 4));                    \
      CVT8(buf_[nf], lo, hi)                                           \
    }                                                                  \
    const char* bA_ = (const char*)&Ab[s_][0];                         \
    _Pragma("unroll") for (int mf = 0; mf < 8; ++mf)                   \
      af[mf] = *(const bf16x8*)(bA_ + rbA + mf * 1024);                \
  }

#define MFMA_STEP()                                                    \
  _Pragma("unroll") for (int mf = 0; mf < 8; ++mf) {                   \
    accg[mf][0] = __builtin_amdgcn_mfma_f32_16x16x32_bf16(af[mf], bgf[0], accg[mf][0], 0, 0, 0); \
    accg[mf][1] = __builtin_amdgcn_mfma_f32_16x16x32_bf16(af[mf], bgf[1], accg[mf][1], 0, 0, 0); \
    accu[mf][0] = __builtin_amdgcn_mfma_f32_16x16x32_bf16(af[mf], buf_[0], accu[mf][0], 0, 0, 0); \
    accu[mf][1] = __builtin_amdgcn_mfma_f32_16x16x32_bf16(af[mf], buf_[1], accu[mf][1], 0, 0, 0); \
  }

__global__ __launch_bounds__(128, 2) void k_gemm1(
    const unsigned short* __restrict__ apad,
    const float* __restrict__ gu,
    const float* __restrict__ wpad,
    const int* __restrict__ meta,
    unsigned short* __restrict__ hpad) {
  int nt = meta[M_NT];
  int active = nt * NCT1;
  int bid = blockIdx.x;
  if (bid >= active) return;
  // bijective XCD chunk swizzle (m204), ct fastest -> A L2-hot per XCD
  int x = bid & 7, idx = bid >> 3;
  int q = active >> 3, r = active & 7;
  int wgid = (x < r ? x * (q + 1) : r * (q + 1) + (x - r) * q) + idx;
  int rt = wgid / NCT1;
  int ct = wgid - rt * NCT1;
  int e = meta[M_RTE + rt], row0 = meta[M_RTR + rt], nv = meta[M_RTV + rt];

  __shared__ __attribute__((aligned(16))) __bf16 Ab[2][128 * 32];   // 16 KB
  __shared__ __attribute__((aligned(16))) float  Bgs[2][64 * 32];   // 16 KB
  __shared__ __attribute__((aligned(16))) float  Bus[2][64 * 32];   // 16 KB

  int tid = threadIdx.x;
  int lane = tid & 63;
  int wn = __builtin_amdgcn_readfirstlane(tid >> 6);   // 0..1 (N-wave)
  int l16 = lane & 15, qd = lane >> 4;
  int tid8 = tid * 8;          // A dest (bf16 elems)
  int tid4 = tid * 4;          // B dest (f32 elems)

  // ---- A staging source (pre-swizzled, pitch 4 chunks): jc = (c&3)^((c>>3)&3)
  int jcA = (tid & 3) ^ ((tid >> 3) & 3);
  int rsA = tid >> 2;                      // 0..31
  const __bf16* pa = (const __bf16*)apad + (size_t)(row0 + rsA) * D_ + jcA * 8;
  // ---- B staging source (fp32, pitch 8 chunks): jc = (tid&7)^((tid>>3)&7)
  int jcB = (tid & 7) ^ ((tid >> 3) & 7);
  int rsB = tid >> 3;                      // 0..15
  const float* pg = gu + ((size_t)e * TWOI_ + (size_t)ct * 64 + rsB) * D_ + jcB * 4;
  const float* pu = pg + (size_t)I_ * D_;

  // ---- ds_read addressing ----
  int swzA = ((qd ^ ((l16 >> 1) & 3)) & 3) * 16;   // A chunk swizzle (bytes)
  int rbA = l16 * 64 + swzA;                        // + mf*1024 bytes
  int loq = ((qd * 2) ^ (l16 & 7)) * 4;             // B f32 chunk (floats)

  floatx4 zero = {0.f, 0.f, 0.f, 0.f};
  floatx4 accg[8][2], accu[8][2];
#pragma unroll
  for (int mf = 0; mf < 8; ++mf) {
    accg[mf][0] = zero; accg[mf][1] = zero;
    accu[mf][0] = zero; accu[mf][1] = zero;
  }

  bf16x8 af[8], bgf[2], buf_[2];

  // ---- prologue ----
  STG(0)
  STG(1)
  asm volatile("s_waitcnt vmcnt(12)" ::: "memory");   // S0 landed
  __builtin_amdgcn_s_barrier();
  SB0()
  RD3(0)

  for (int t = 0; t < 62; ++t) {
    int s = t & 1;
    asm volatile("s_waitcnt lgkmcnt(0)" ::: "memory");  // frags(t) ready
    SB0()
    __builtin_amdgcn_s_setprio(1);
    MFMA_STEP()
    __builtin_amdgcn_s_setprio(0);
    __builtin_amdgcn_s_barrier();          // both waves done reading slot s
    SB0()
    STG(s)                                  // stage S(t+2) -> slot s
    asm volatile("s_waitcnt vmcnt(12)" ::: "memory");   // S(t+1) landed
    __builtin_amdgcn_s_barrier();          // S(t+1) visible to both waves
    SB0()
    RD3((t + 1) & 1)                        // frags(t+1)
  }
  // t = 62 (no stage)
  asm volatile("s_waitcnt lgkmcnt(0)" ::: "memory");
  SB0()
  __builtin_amdgcn_s_setprio(1);
  MFMA_STEP()
  __builtin_amdgcn_s_setprio(0);
  asm volatile("s_waitcnt vmcnt(0)" ::: "memory");      // S(63) landed
  __builtin_amdgcn_s_barrier();
  SB0()
  RD3(1)
  // t = 63
  asm volatile("s_waitcnt lgkmcnt(0)" ::: "memory");
  SB0()
  __builtin_amdgcn_s_setprio(1);
  MFMA_STEP()
  __builtin_amdgcn_s_setprio(0);

  // ---- epilogue: SwiGLU + routing weight -> hpad ----
#pragma unroll
  for (int mf = 0; mf < 8; ++mf)
#pragma unroll
    for (int reg = 0; reg < 4; ++reg) {
      int rr = mf * 16 + qd * 4 + reg;
      if (rr < nv) {
        float wgt = wpad[row0 + rr];
        unsigned short* hrow = hpad + (size_t)(row0 + rr) * I_ +
                               (size_t)ct * 64 + wn * 32 + l16;
#pragma unroll
        for (int nf = 0; nf < 2; ++nf) {
          float g = accg[mf][nf][reg];
          float uu = accu[mf][nf][reg];
          float sg = g / (1.f + __expf(-g));
          hrow[nf * 16] = f2bf(sg * uu * wgt);
        }
      }
    }
}

// =====================================================================
// GEMM2: out = h @ down^T; down read DIRECTLY as fp32 (no cvt), in-reg
// conversion after ds_read. XOR swizzle added to As (bf16) and Bs (f32).
// =====================================================================
__global__ __launch_bounds__(256) void k_gemm2(
    const unsigned short* __restrict__ hpad,
    const float* __restrict__ dn,
    const int* __restrict__ meta,
    const int* __restrict__ perm,
    float* __restrict__ out) {
  int bid = blockIdx.x;
  int panel = bid / 128;            // 16 ct * 8 rt
  int rem = bid - panel * 128;
  int ct = rem >> 3;                // 0..15
  int rt = panel * 8 + (rem & 7);
  if (rt >= meta[M_NT]) return;
  int e = meta[M_RTE + rt], row0 = meta[M_RTR + rt], nv = meta[M_RTV + rt];

  __shared__ __attribute__((aligned(16))) __bf16 As[2][128 * 32];   // 16 KB
  __shared__ __attribute__((aligned(16))) float  Bs[2][128 * 32];   // 32 KB

  int tid = threadIdx.x;
  int lane = tid & 63;
  int l16 = lane & 15, qd = lane >> 4;
  int wave = __builtin_amdgcn_readfirstlane(tid >> 6);
  int wm = wave >> 1, wn = wave & 1;

  // A staging (bf16, pre-swizzled pitch-4): c = g*256+tid, row=c>>2
  int jcA = (tid & 3) ^ ((tid >> 3) & 3);
  const __bf16* A = (const __bf16*)hpad + (size_t)(row0 + (tid >> 2)) * I_ + jcA * 8;
  // B staging (fp32, pre-swizzled pitch-8): c = g*256+tid, row=c>>3
  int jcB = (tid & 7) ^ ((tid >> 3) & 7);
  const float* B = dn + ((size_t)e * D_ + (size_t)ct * 128 + (tid >> 3)) * I_ + jcB * 4;

  floatx4 zero = {0.f, 0.f, 0.f, 0.f};
  floatx4 acc[4][4];
#pragma unroll
  for (int mi = 0; mi < 4; ++mi)
#pragma unroll
    for (int ni = 0; ni < 4; ++ni) acc[mi][ni] = zero;

  int swzA = ((qd ^ ((l16 >> 1) & 3)) & 3) * 16;   // A byte chunk
  int loq = ((qd * 2) ^ (l16 & 7)) * 4;             // B float chunk

  for (int k0 = 0; k0 < I_; k0 += 64) {
#pragma unroll
    for (int p = 0; p < 2; ++p) {
      int kk = k0 + p * 32;
      // A: 128 rows x 4 chunks = 512 chunks, 2 gloads/thread
      gload16(A + kk, &As[p][tid * 8]);
      gload16(A + (size_t)64 * I_ + kk, &As[p][2048 + tid * 8]);
      // B: 128 rows x 8 chunks = 1024 chunks, 4 gloads/thread
      gload16(B + kk, &Bs[p][tid * 4]);
      gload16(B + (size_t)32 * I_ + kk, &Bs[p][1024 + tid * 4]);
      gload16(B + (size_t)64 * I_ + kk, &Bs[p][2048 + tid * 4]);
      gload16(B + (size_t)96 * I_ + kk, &Bs[p][3072 + tid * 4]);
    }
    __syncthreads();
#pragma unroll
    for (int p = 0; p < 2; ++p) {
      bf16x8 af[4], bfr[4];
#pragma unroll
      for (int mi = 0; mi < 4; ++mi)
        af[mi] = *(const bf16x8*)((const char*)&As[p][0] +
                                  (wm * 64 + mi * 16 + l16) * 64 + swzA);
#pragma unroll
      for (int ni = 0; ni < 4; ++ni) {
        const float* rw = &Bs[p][(wn * 64 + ni * 16 + l16) * 32];
        float4 lo = *(const float4*)(rw + loq);
        float4 hi = *(const float4*)(rw + (loq ^ 4));
        CVT8(bfr[ni], lo, hi)
      }
#pragma unroll
      for (int mi = 0; mi < 4; ++mi)
#pragma unroll
        for (int ni = 0; ni < 4; ++ni)
          acc[mi][ni] = __builtin_amdgcn_mfma_f32_16x16x32_bf16(af[mi], bfr[ni], acc[mi][ni], 0, 0, 0);
    }
    __syncthreads();
  }

#pragma unroll
  for (int mi = 0; mi < 4; ++mi)
#pragma unroll
    for (int reg = 0; reg < 4; ++reg) {
      int r = wm * 64 + mi * 16 + qd * 4 + reg;
      if (r < nv) {
        int t = perm[row0 + r];
        float* orow = out + (size_t)t * D_ + (size_t)ct * 128 + wn * 64;
#pragma unroll
        for (int ni = 0; ni < 4; ++ni)
          orow[ni * 16 + l16] = acc[mi][ni][reg];
      }
    }
}

// -------------- fallback (tiny ws): correct but slow --------------
__global__ __launch_bounds__(256) void k_naive(
    const float* __restrict__ tokens, const int* __restrict__ ids,
    const float* __restrict__ w, const float* __restrict__ gu,
    const float* __restrict__ dn, float* __restrict__ out) {
  __shared__ float tok[D_];
  __shared__ float h[I_];
  int t = blockIdx.x;
  int e = ids[t];
  float wgt = w[t];
  for (int i = threadIdx.x; i < D_; i += 256) tok[i] = tokens[(size_t)t * D_ + i];
  __syncthreads();
  for (int j = threadIdx.x; j < I_; j += 256) {
    const float* wg = gu + ((size_t)e * TWOI_ + j) * D_;
    const float* wu = wg + (size_t)I_ * D_;
    float g = 0.f, u = 0.f;
    for (int k = 0; k < D_; ++k) { g += tok[k] * wg[k]; u += tok[k] * wu[k]; }
    h[j] = g / (1.f + __expf(-g)) * u * wgt;
  }
  __syncthreads();
  for (int d = threadIdx.x; d < D_; d += 256) {
    const float* wd = dn + ((size_t)e * D_ + d) * I_;
    float acc = 0.f;
    for (int k = 0; k < I_; ++k) acc += h[k] * wd[k];
    out[(size_t)t * D_ + d] = acc;
  }
}

extern "C" void kernel_launch(void* const* d_in, const int* in_sizes, int n_in,
                              void* d_out, int out_size, void* d_ws, size_t ws_size,
                              hipStream_t stream) {
  const float* tokens = (const float*)d_in[0];
  const int*   ids    = (const int*)d_in[1];
  const float* wts    = (const float*)d_in[2];
  const float* gu     = (const float*)d_in[3];
  const float* dn     = (const float*)d_in[4];
  float* out = (float*)d_out;

  if (ws_size < (size_t)WS_NEED) {
    k_naive<<<N_, 256, 0, stream>>>(tokens, ids, wts, gu, dn, out);
    return;
  }

  char* ws = (char*)d_ws;
  int* meta = (int*)ws;
  int* perm = (int*)(ws + OFF_PERM);
  float* wpad = (float*)(ws + OFF_WPAD);
  unsigned short* apad = (unsigned short*)(ws + OFF_APAD);
  unsigned short* hpad = (unsigned short*)(ws + OFF_HPAD);

  hipMemsetAsync(meta, 0, 64, stream);                 // cnt + cur
  hipMemsetAsync(perm, 0xFF, MPAD * 4, stream);        // perm = -1
  k_hist<<<N_ / 256, 256, 0, stream>>>(ids, meta);
  k_meta<<<1, 1, 0, stream>>>(meta);
  k_scatter<<<N_ / 256, 256, 0, stream>>>(ids, wts, meta, perm, wpad);
  k_gather<<<MPAD, 256, 0, stream>>>(tokens, perm, apad);
  k_gemm1<<<MAXTILES * NCT1, 128, 0, stream>>>(apad, gu, wpad, meta, hpad);
  k_gemm2<<<9 * 128, 256, 0, stream>>>(hpad, dn, meta, perm, out);
}